// Round 1
// baseline (310.083 us; speedup 1.0000x reference)
//
#include <hip/hip_runtime.h>
#include <math.h>

// CFConv: out[a][f] = sum_n x[nbr[a][n]][f] * W[a][n][f]
//   W = (softplus(rbf @ w1 + b1)) @ w2 + b2
// N=20000 atoms, NB=32 neighbors, F=128, RBF=64.
//
// Structure: 512-thread blocks (8 waves). Each wave owns ONE atom per tile
// (32 pair-rows = 2 MFMA M-tiles). Weights live in LDS in MFMA B-fragment
// layout (prepacked once per block). One __syncthreads total; everything
// after is wave-local (each wave touches only its own 32-row hbuf band).

#define NATOMS 20000
#define NB     32
#define FD     128
#define RD     64
#define WAVES  8           // waves per block = atoms per tile
#define NTILES 2500        // 20000 / 8
#define HSTR   136         // bf16 row stride for hbuf: 272B, mult of 16 (b128-aligned), breaks bank aliasing

typedef short  short8  __attribute__((ext_vector_type(8)));
typedef float  floatx4 __attribute__((ext_vector_type(4)));
typedef float  floatx2 __attribute__((ext_vector_type(2)));

static __device__ __forceinline__ short f2bf(float f) {
  // round-to-nearest-even fp32 -> bf16
  unsigned u = __builtin_bit_cast(unsigned, f);
  u = (u + 0x7FFFu + ((u >> 16) & 1u)) >> 16;
  return (short)u;
}

static __device__ __forceinline__ float softplus(float v) {
  // stable: max(v,0) + log(1 + exp(-|v|)); arg of exp <= 0 so no overflow.
  return fmaxf(v, 0.0f) + __logf(1.0f + __expf(-fabsf(v)));
}

__global__ __launch_bounds__(512)
void cfconv_kernel(const float* __restrict__ x,
                   const float* __restrict__ rbf,
                   const int*   __restrict__ nbr,
                   const float* __restrict__ w1,
                   const float* __restrict__ b1,
                   const float* __restrict__ w2,
                   const float* __restrict__ b2,
                   float* __restrict__ out) {
  // B-fragment layout: frag[kt*8+nt][lane][j] = B[kt*32 + (lane>>4)*8 + j][nt*16 + (lane&15)]
  __shared__ __align__(16) short w1f[16][64][8];          // 16 KB
  __shared__ __align__(16) short w2f[32][64][8];          // 32 KB
  __shared__ __align__(16) short hbuf[WAVES * 32][HSTR];  // ~68 KB, H then W (bf16), per-wave bands

  const int tid  = threadIdx.x;
  const int lane = tid & 63;
  const int wv   = tid >> 6;
  const int q    = lane >> 4;   // k-quad inside a fragment
  const int ln   = lane & 15;   // m (A/C) or n (B) inside a 16-tile

  // ---- prepack weights: coalesced fp32 global reads -> bf16 B-frags in LDS ----
  for (int i = tid; i < RD * FD; i += 512) {
    int k = i >> 7, n = i & 127, kk = k & 31;
    w1f[(k >> 5) * 8 + (n >> 4)][(kk >> 3) * 16 + (n & 15)][kk & 7] = f2bf(w1[i]);
  }
  for (int i = tid; i < FD * FD; i += 512) {
    int k = i >> 7, n = i & 127, kk = k & 31;
    w2f[(k >> 5) * 8 + (n >> 4)][(kk >> 3) * 16 + (n & 15)][kk & 7] = f2bf(w2[i]);
  }
  float b1v[8], b2v[8];
#pragma unroll
  for (int nt = 0; nt < 8; ++nt) {
    b1v[nt] = b1[nt * 16 + ln];
    b2v[nt] = b2[nt * 16 + ln];
  }
  __syncthreads();  // the only barrier; all hbuf use below is wave-private

  for (int tile = blockIdx.x; tile < NTILES; tile += gridDim.x) {
    const int atom = tile * WAVES + wv;
    const int prow = atom * NB;     // first (atom,neighbor) pair-row for this wave
    const int hrow = wv * 32;       // this wave's band in hbuf

    // ---- rbf A-fragments from global: A[m=ln][k=q*8+j], fp32 -> bf16 ----
    short8 afrag[2][2];
#pragma unroll
    for (int mt = 0; mt < 2; ++mt) {
      const float* src = rbf + (prow + mt * 16 + ln) * RD + q * 8;
#pragma unroll
      for (int kt = 0; kt < 2; ++kt) {
        floatx4 lo = *(const floatx4*)(src + kt * 32);
        floatx4 hi = *(const floatx4*)(src + kt * 32 + 4);
        short8 f;
        f[0] = f2bf(lo[0]); f[1] = f2bf(lo[1]); f[2] = f2bf(lo[2]); f[3] = f2bf(lo[3]);
        f[4] = f2bf(hi[0]); f[5] = f2bf(hi[1]); f[6] = f2bf(hi[2]); f[7] = f2bf(hi[3]);
        afrag[mt][kt] = f;
      }
    }

    // ---- GEMM1: H = softplus(rbf @ w1 + b1), 2x8 C-tiles, K=64 (2 steps) ----
    floatx4 acc1[2][8];
#pragma unroll
    for (int mt = 0; mt < 2; ++mt)
#pragma unroll
      for (int nt = 0; nt < 8; ++nt)
        acc1[mt][nt] = floatx4{0.f, 0.f, 0.f, 0.f};
#pragma unroll
    for (int kt = 0; kt < 2; ++kt)
#pragma unroll
      for (int nt = 0; nt < 8; ++nt) {
        short8 bfrag = *(const short8*)&w1f[kt * 8 + nt][lane][0];
#pragma unroll
        for (int mt = 0; mt < 2; ++mt)
          acc1[mt][nt] = __builtin_amdgcn_mfma_f32_16x16x32_bf16(
              afrag[mt][kt], bfrag, acc1[mt][nt], 0, 0, 0);
      }

    // C/D layout: value r of lane -> (row = q*4 + r, col = ln) within 16x16 tile
#pragma unroll
    for (int mt = 0; mt < 2; ++mt)
#pragma unroll
      for (int nt = 0; nt < 8; ++nt)
#pragma unroll
        for (int r = 0; r < 4; ++r)
          hbuf[hrow + mt * 16 + q * 4 + r][nt * 16 + ln] =
              f2bf(softplus(acc1[mt][nt][r] + b1v[nt]));

    // ---- H A-fragments back from LDS (row-contiguous -> ds_read_b128) ----
    short8 hfrag[2][4];
#pragma unroll
    for (int mt = 0; mt < 2; ++mt)
#pragma unroll
      for (int kt = 0; kt < 4; ++kt)
        hfrag[mt][kt] = *(const short8*)&hbuf[hrow + mt * 16 + ln][kt * 32 + q * 8];

    // ---- GEMM2: W = H @ w2 + b2, K=128 (4 steps) ----
    floatx4 acc2[2][8];
#pragma unroll
    for (int mt = 0; mt < 2; ++mt)
#pragma unroll
      for (int nt = 0; nt < 8; ++nt)
        acc2[mt][nt] = floatx4{0.f, 0.f, 0.f, 0.f};
#pragma unroll
    for (int kt = 0; kt < 4; ++kt)
#pragma unroll
      for (int nt = 0; nt < 8; ++nt) {
        short8 bfrag = *(const short8*)&w2f[kt * 8 + nt][lane][0];
#pragma unroll
        for (int mt = 0; mt < 2; ++mt)
          acc2[mt][nt] = __builtin_amdgcn_mfma_f32_16x16x32_bf16(
              hfrag[mt][kt], bfrag, acc2[mt][nt], 0, 0, 0);
      }

    // ---- W (bf16) back into the same wave-private band (reads above already consumed) ----
#pragma unroll
    for (int mt = 0; mt < 2; ++mt)
#pragma unroll
      for (int nt = 0; nt < 8; ++nt)
#pragma unroll
        for (int r = 0; r < 4; ++r)
          hbuf[hrow + mt * 16 + q * 4 + r][nt * 16 + ln] =
              f2bf(acc2[mt][nt][r] + b2v[nt]);

    // ---- epilogue: out[atom][f] = sum_r x[nbr[r]][f] * W[r][f] ----
    // lane covers f = {2*lane, 2*lane+1}; nbr index is wave-uniform -> s_load;
    // x row read is one coalesced global_load_dwordx2 per row.
    const int* nbp = nbr + atom * NB;
    float o0 = 0.f, o1 = 0.f;
#pragma unroll 8
    for (int r = 0; r < NB; ++r) {
      int j = nbp[r];
      floatx2 xv = *(const floatx2*)(x + j * FD + lane * 2);
      unsigned pw = *(const unsigned*)&hbuf[hrow + r][lane * 2];  // 2 bf16, conflict-free
      o0 += xv[0] * __builtin_bit_cast(float, pw << 16);
      o1 += xv[1] * __builtin_bit_cast(float, pw & 0xFFFF0000u);
    }
    *(floatx2*)(out + atom * FD + lane * 2) = floatx2{o0, o1};
  }
}

extern "C" void kernel_launch(void* const* d_in, const int* in_sizes, int n_in,
                              void* d_out, int out_size, void* d_ws, size_t ws_size,
                              hipStream_t stream) {
  const float* x   = (const float*)d_in[0];
  const float* rbf = (const float*)d_in[1];
  const int*   nbr = (const int*)d_in[2];   // harness delivers integer inputs as int32
  const float* w1  = (const float*)d_in[3];
  const float* b1  = (const float*)d_in[4];
  const float* w2  = (const float*)d_in[5];
  const float* b2  = (const float*)d_in[6];
  float* out = (float*)d_out;

  // 119 KB LDS -> 1 block/CU; grid-stride over 2500 tiles from 256 blocks
  // (weights prepacked once per block, not once per tile).
  cfconv_kernel<<<dim3(256), dim3(512), 0, stream>>>(x, rbf, nbr, w1, b1, w2, b2, out);
}